// Round 1
// baseline (440.892 us; speedup 1.0000x reference)
//
#include <hip/hip_runtime.h>

// o[i,u,j] = sum_{v<=u} t[v,j] * x[i,v,j]
// x: (b, n, d) fp32, t: (2n-2, d) fp32 (first n rows used), o: (b, n, d) fp32

typedef float f4 __attribute__((ext_vector_type(4)));

#define D  512
#define DV (D / 4)    // 128 float4 columns
#define C  128        // chunks along sequence
#define RS 4          // row-group split inside a block
#define RT 16         // rows per thread in single-pass kernel (L = RS*RT = 64)
#define NT (DV * RS)  // 512 threads

// ---------------- Single-pass decoupled-lookback scan ----------------
// One kernel: reads x/t once, keeps products in VGPRs, publishes chunk
// aggregates with agent-scope release flags, ticket-ordered for progress.
__global__ __launch_bounds__(NT) void k_scan1(
    const float* __restrict__ x, const float* __restrict__ t,
    float* S, unsigned int* flags, unsigned int* ticket,
    float* __restrict__ o, int b, int n) {
  __shared__ unsigned int s_vid;
  __shared__ f4 redA[RS][DV];   // per-row-group chunk partials (phase A)
  __shared__ f4 redB[RS][DV];   // per-row-group lookback partials (phase B)

  const int tid = threadIdx.x;
  if (tid == 0)
    s_vid = __hip_atomic_fetch_add(ticket, 1u, __ATOMIC_RELAXED,
                                   __HIP_MEMORY_SCOPE_AGENT);
  __syncthreads();
  const int vid = (int)s_vid;          // virtual block id = start order
  const int c   = vid / b;             // chunk index (monotone in start order)
  const int i   = vid - c * b;         // batch index
  const int jv  = tid & (DV - 1);
  const int h   = tid >> 7;            // row group 0..3
  const int L   = RS * RT;             // 64

  const size_t row0 = (size_t)c * L + (size_t)h * RT;
  const f4* xp = (const f4*)x + ((size_t)i * n + row0) * DV + jv;
  const f4* tp = (const f4*)t + row0 * DV + jv;

  // Phase A: load chunk once, keep products in registers (64 VGPRs).
  f4 p[RT];
  f4 psum = {0.f, 0.f, 0.f, 0.f};
#pragma unroll
  for (int r = 0; r < RT; ++r) {
    p[r] = xp[(size_t)r * DV] * tp[(size_t)r * DV];
    psum += p[r];
  }
  redA[h][jv] = psum;
  __syncthreads();

  // Publish chunk aggregate S[c][i][:] then release the flag.
  if (h == 0) {
    f4 s = redA[0][jv] + redA[1][jv] + redA[2][jv] + redA[3][jv];
    ((f4*)S)[((size_t)c * b + i) * DV + jv] = s;
  }
  __syncthreads();  // compiler drains vmcnt before s_barrier: S is in L2
  if (tid == 0)
    __hip_atomic_store(&flags[(size_t)c * b + i], 1u, __ATOMIC_RELEASE,
                       __HIP_MEMORY_SCOPE_AGENT);

  // Phase B: wait for all predecessor chunks of this batch row.
  // Safe: any (c'<c, i) block holds a smaller ticket => already started
  // on some CU and publishes its flag before doing its own lookback.
  for (int cp = tid; cp < c; cp += NT) {
    while (__hip_atomic_load(&flags[(size_t)cp * b + i], __ATOMIC_RELAXED,
                             __HIP_MEMORY_SCOPE_AGENT) == 0u)
      __builtin_amdgcn_s_sleep(2);
  }
  __syncthreads();
  __threadfence();  // agent-scope acquire: invalidate stale L1/L2 lines for S

  // Exclusive prefix = sum of predecessor aggregates (pipelined, L2/L3-hot).
  f4 ex = {0.f, 0.f, 0.f, 0.f};
  const f4* Sp = (const f4*)S + (size_t)i * DV + jv;
  const size_t cs = (size_t)b * DV;
#pragma unroll 4
  for (int cp = h; cp < c; cp += RS)
    ex += Sp[(size_t)cp * cs];
  redB[h][jv] = ex;
  __syncthreads();
  f4 base = redB[0][jv] + redB[1][jv] + redB[2][jv] + redB[3][jv];
  for (int hp = 0; hp < h; ++hp)   // within-chunk prefix of earlier row groups
    base += redA[hp][jv];

  // Phase C: in-register scan + store (x never re-read).
  f4* op = (f4*)o + ((size_t)i * n + row0) * DV + jv;
  f4 acc = base;
#pragma unroll
  for (int r = 0; r < RT; ++r) {
    acc += p[r];
    op[(size_t)r * DV] = acc;
  }
}

// ---------------- Fallback: previous two-kernel pipeline ----------------
__global__ __launch_bounds__(DV * RS) void k_chunksum(
    const float* __restrict__ x, const float* __restrict__ t,
    float* __restrict__ S, int b, int n, int L) {
  const int c  = blockIdx.x / b;
  const int i  = blockIdx.x % b;
  const int jv = threadIdx.x & (DV - 1);
  const int h  = threadIdx.x >> 7;
  const int rows = L / RS;
  const size_t row0 = (size_t)c * L + (size_t)h * rows;
  const f4* xp = (const f4*)x + ((size_t)i * n + row0) * DV + jv;
  const f4* tp = (const f4*)t + row0 * DV + jv;
  f4 acc = {0.f, 0.f, 0.f, 0.f};
#pragma unroll 8
  for (int v = 0; v < rows; ++v) {
    acc += xp[(size_t)v * DV] * tp[(size_t)v * DV];
  }
  __shared__ f4 red[RS][DV];
  red[h][jv] = acc;
  __syncthreads();
  if (h == 0) {
    f4 s = red[0][jv] + red[1][jv] + red[2][jv] + red[3][jv];
    ((f4*)S)[((size_t)c * b + i) * DV + jv] = s;
  }
}

__global__ __launch_bounds__(DV) void k_out(
    const float* __restrict__ x, const float* __restrict__ t,
    const float* __restrict__ S, float* __restrict__ o, int b, int n, int L) {
  const int c  = blockIdx.x / b;
  const int i  = blockIdx.x % b;
  const int jv = threadIdx.x;
  f4 acc = {0.f, 0.f, 0.f, 0.f};
  const f4* Sp = (const f4*)S + (size_t)i * DV + jv;
  const size_t cstride = (size_t)b * DV;
#pragma unroll 8
  for (int cp = 0; cp < c; ++cp) {
    acc += Sp[(size_t)cp * cstride];
  }
  const size_t row0  = (size_t)c * L;
  const size_t xbase = ((size_t)i * n + row0) * DV + jv;
  const f4* xp = (const f4*)x + xbase;
  const f4* tp = (const f4*)t + row0 * DV + jv;
  f4*       op = (f4*)o + xbase;
#pragma unroll 4
  for (int v = 0; v < L; ++v) {
    acc += xp[(size_t)v * DV] * tp[(size_t)v * DV];
    op[(size_t)v * DV] = acc;
  }
}

__global__ __launch_bounds__(256) void k_naive(
    const float* __restrict__ x, const float* __restrict__ t,
    float* __restrict__ o, int b, int n) {
  const int tid = blockIdx.x * 256 + threadIdx.x;
  if (tid >= b * DV) return;
  const int i  = tid / DV;
  const int jv = tid % DV;
  const f4* xp = (const f4*)x + (size_t)i * n * DV + jv;
  const f4* tp = (const f4*)t + jv;
  f4*       op = (f4*)o + (size_t)i * n * DV + jv;
  f4 acc = {0.f, 0.f, 0.f, 0.f};
  for (int v = 0; v < n; ++v) {
    acc += xp[(size_t)v * DV] * tp[(size_t)v * DV];
    op[(size_t)v * DV] = acc;
  }
}

extern "C" void kernel_launch(void* const* d_in, const int* in_sizes, int n_in,
                              void* d_out, int out_size, void* d_ws, size_t ws_size,
                              hipStream_t stream) {
  const float* x = (const float*)d_in[0];
  const float* t = (const float*)d_in[1];
  float*       o = (float*)d_out;

  const long long t_elems = in_sizes[1];
  const int n = (int)((t_elems / D + 2) / 2);
  const int b = (int)((long long)in_sizes[0] / ((long long)n * D));

  const size_t sBytes = (size_t)C * b * D * sizeof(float);   // aggregates (2 MB)
  const size_t fBytes = (size_t)C * b * sizeof(unsigned);    // flags (4 KB)
  const size_t need1  = sBytes + fBytes + 256;

  if (n == C * RS * RT && b >= 1 && ws_size >= need1) {
    float*        S      = (float*)d_ws;
    unsigned int* flags  = (unsigned int*)((char*)d_ws + sBytes);
    unsigned int* ticket = (unsigned int*)((char*)d_ws + sBytes + fBytes);
    // Zero flags + ticket (graph-capturable async op).
    hipMemsetAsync((char*)d_ws + sBytes, 0, fBytes + 64, stream);
    hipLaunchKernelGGL(k_scan1, dim3(C * b), dim3(NT), 0, stream,
                       x, t, S, flags, ticket, o, b, n);
  } else if (n % C == 0 && (n / C) % RS == 0 && ws_size >= sBytes) {
    const int L = n / C;
    float* S = (float*)d_ws;
    hipLaunchKernelGGL(k_chunksum, dim3(C * b), dim3(DV * RS), 0, stream,
                       x, t, S, b, n, L);
    hipLaunchKernelGGL(k_out, dim3(C * b), dim3(DV), 0, stream,
                       x, t, S, o, b, n, L);
  } else {
    const int threads = b * DV;
    hipLaunchKernelGGL(k_naive, dim3((threads + 255) / 256), dim3(256), 0, stream,
                       x, t, o, b, n);
  }
}

// Round 3
// 285.843 us; speedup vs baseline: 1.5424x; 1.5424x over previous
//
#include <hip/hip_runtime.h>

// o[i,u,j] = sum_{v<=u} t[v,j] * x[i,v,j]
// x: (b, n, d) fp32, t: (2n-2, d) fp32 (first n rows used), o: (b, n, d) fp32

typedef float f4 __attribute__((ext_vector_type(4)));

#define D  512
#define DV (D / 4)    // 128 float4 columns
#define C  128        // chunks along sequence
#define RS 4          // row-group split inside a block
#define RT 16         // rows per thread (L = RS*RT = 64)
#define NT (DV * RS)  // 512 threads

// Write-through coherent 16B store (reaches coherence point, no cache sweep).
__device__ __forceinline__ void coh_store_f4(f4* p, f4 v) {
  asm volatile("global_store_dwordx4 %0, %1, off sc0 sc1"
               :: "v"(p), "v"(v) : "memory");
}

// ---------------- Single-pass decoupled-lookback scan, v2 ----------------
// No release fences / no __threadfence (those emit L2 writeback sweeps on
// gfx950 — round-1 showed 0.7 TB/s, VALUBusy 1.3%). Transport is explicit:
// coherent write-through S stores + vmcnt drain + relaxed flag.
// No acquire fence needed: each S row is line-exclusive to one (c,i), and
// readers touch it only after its flag (sc1 atomic load) is observed, so no
// stale copy can exist anywhere. __syncthreads() gives compiler ordering.
__global__ __launch_bounds__(NT, 6) void k_scan1(
    const float* __restrict__ x, const float* __restrict__ t,
    float* S, unsigned int* flags, unsigned int* ticket,
    float* __restrict__ o, int b, int n) {
  __shared__ unsigned int s_vid;
  __shared__ f4 red[RS][DV];   // 8 KB, reused across phases

  const int tid = threadIdx.x;
  if (tid == 0)
    s_vid = __hip_atomic_fetch_add(ticket, 1u, __ATOMIC_RELAXED,
                                   __HIP_MEMORY_SCOPE_AGENT);
  __syncthreads();
  const int vid = (int)s_vid;          // start-order virtual block id
  const int c   = vid / b;             // chunk (monotone in start order)
  const int i   = vid - c * b;         // batch row
  const int jv  = tid & (DV - 1);
  const int h   = tid >> 7;            // row group 0..3
  const int L   = RS * RT;             // 64

  const size_t row0 = (size_t)c * L + (size_t)h * RT;
  const f4* xp = (const f4*)x + ((size_t)i * n + row0) * DV + jv;
  const f4* tp = (const f4*)t + row0 * DV + jv;

  // Phase A: read chunk once; products stay in VGPRs. x is single-use ->
  // nontemporal; t is reused across the 8 batch rows -> cached.
  f4 p[RT];
  f4 psum = {0.f, 0.f, 0.f, 0.f};
#pragma unroll
  for (int r = 0; r < RT; ++r) {
    f4 xv = __builtin_nontemporal_load(xp + (size_t)r * DV);
    f4 tv = tp[(size_t)r * DV];
    p[r] = xv * tv;
    psum += p[r];
  }
  red[h][jv] = psum;
  __syncthreads();

  // Within-chunk exclusive base for this row group (save now; red is reused).
  f4 baseL = {0.f, 0.f, 0.f, 0.f};
  for (int hp = 0; hp < h; ++hp) baseL += red[hp][jv];

  // Publish chunk aggregate write-through coherent, then relaxed flag.
  if (h == 0) {
    f4 s = red[0][jv] + red[1][jv] + red[2][jv] + red[3][jv];
    coh_store_f4((f4*)S + ((size_t)c * b + i) * DV + jv, s);
  }
  asm volatile("s_waitcnt vmcnt(0)" ::: "memory");
  __syncthreads();
  if (tid == 0)
    __hip_atomic_store(&flags[(size_t)i * C + c], 1u, __ATOMIC_RELAXED,
                       __HIP_MEMORY_SCOPE_AGENT);

  // Phase B: wave 0 polls predecessors' flags (contiguous -> coalesced).
  if (tid < 64) {
    const unsigned int* fp = flags + (size_t)i * C;
    const int c0 = tid, c1 = tid + 64;
    const bool need0 = c0 < c, need1 = c1 < c;
    for (;;) {
      bool ok0 = !need0 || (__hip_atomic_load(fp + c0, __ATOMIC_RELAXED,
                                              __HIP_MEMORY_SCOPE_AGENT) != 0u);
      bool ok1 = !need1 || (__hip_atomic_load(fp + c1, __ATOMIC_RELAXED,
                                              __HIP_MEMORY_SCOPE_AGENT) != 0u);
      if (__all(ok0 && ok1)) break;
      __builtin_amdgcn_s_sleep(2);
    }
  }
  __syncthreads();   // compiler + workgroup fence; S lines are fresh per-line

  // Exclusive prefix: plain pipelined loads of S.
  f4 ex = {0.f, 0.f, 0.f, 0.f};
  const f4* Sb = (const f4*)S;
#pragma unroll 8
  for (int cp = h; cp < c; cp += RS)
    ex += Sb[((size_t)cp * b + i) * DV + jv];
  red[h][jv] = ex;
  __syncthreads();
  f4 base = red[0][jv] + red[1][jv] + red[2][jv] + red[3][jv] + baseL;

  // Phase C: in-register scan + nontemporal stores (x never re-read).
  f4* op = (f4*)o + ((size_t)i * n + row0) * DV + jv;
  f4 acc = base;
#pragma unroll
  for (int r = 0; r < RT; ++r) {
    acc += p[r];
    __builtin_nontemporal_store(acc, op + (size_t)r * DV);
  }
}

// ---------------- Fallback: two-kernel pipeline ----------------
__global__ __launch_bounds__(DV * RS) void k_chunksum(
    const float* __restrict__ x, const float* __restrict__ t,
    float* __restrict__ S, int b, int n, int L) {
  const int c  = blockIdx.x / b;
  const int i  = blockIdx.x % b;
  const int jv = threadIdx.x & (DV - 1);
  const int h  = threadIdx.x >> 7;
  const int rows = L / RS;
  const size_t row0 = (size_t)c * L + (size_t)h * rows;
  const f4* xp = (const f4*)x + ((size_t)i * n + row0) * DV + jv;
  const f4* tp = (const f4*)t + row0 * DV + jv;
  f4 acc = {0.f, 0.f, 0.f, 0.f};
#pragma unroll 8
  for (int v = 0; v < rows; ++v) {
    acc += xp[(size_t)v * DV] * tp[(size_t)v * DV];
  }
  __shared__ f4 red[RS][DV];
  red[h][jv] = acc;
  __syncthreads();
  if (h == 0) {
    f4 s = red[0][jv] + red[1][jv] + red[2][jv] + red[3][jv];
    ((f4*)S)[((size_t)c * b + i) * DV + jv] = s;
  }
}

__global__ __launch_bounds__(DV) void k_out(
    const float* __restrict__ x, const float* __restrict__ t,
    const float* __restrict__ S, float* __restrict__ o, int b, int n, int L) {
  const int c  = blockIdx.x / b;
  const int i  = blockIdx.x % b;
  const int jv = threadIdx.x;
  f4 acc = {0.f, 0.f, 0.f, 0.f};
  const f4* Sp = (const f4*)S + (size_t)i * DV + jv;
  const size_t cstride = (size_t)b * DV;
#pragma unroll 8
  for (int cp = 0; cp < c; ++cp) {
    acc += Sp[(size_t)cp * cstride];
  }
  const size_t row0  = (size_t)c * L;
  const size_t xbase = ((size_t)i * n + row0) * DV + jv;
  const f4* xp = (const f4*)x + xbase;
  const f4* tp = (const f4*)t + row0 * DV + jv;
  f4*       op = (f4*)o + xbase;
#pragma unroll 4
  for (int v = 0; v < L; ++v) {
    acc += xp[(size_t)v * DV] * tp[(size_t)v * DV];
    op[(size_t)v * DV] = acc;
  }
}

__global__ __launch_bounds__(256) void k_naive(
    const float* __restrict__ x, const float* __restrict__ t,
    float* __restrict__ o, int b, int n) {
  const int tid = blockIdx.x * 256 + threadIdx.x;
  if (tid >= b * DV) return;
  const int i  = tid / DV;
  const int jv = tid % DV;
  const f4* xp = (const f4*)x + (size_t)i * n * DV + jv;
  const f4* tp = (const f4*)t + jv;
  f4*       op = (f4*)o + (size_t)i * n * DV + jv;
  f4 acc = {0.f, 0.f, 0.f, 0.f};
  for (int v = 0; v < n; ++v) {
    acc += xp[(size_t)v * DV] * tp[(size_t)v * DV];
    op[(size_t)v * DV] = acc;
  }
}

extern "C" void kernel_launch(void* const* d_in, const int* in_sizes, int n_in,
                              void* d_out, int out_size, void* d_ws, size_t ws_size,
                              hipStream_t stream) {
  const float* x = (const float*)d_in[0];
  const float* t = (const float*)d_in[1];
  float*       o = (float*)d_out;

  const long long t_elems = in_sizes[1];
  const int n = (int)((t_elems / D + 2) / 2);
  const int b = (int)((long long)in_sizes[0] / ((long long)n * D));

  const size_t sBytes = (size_t)C * b * D * sizeof(float);   // aggregates (2 MB)
  const size_t fBytes = (size_t)C * b * sizeof(unsigned);    // flags (4 KB)
  const size_t need1  = sBytes + fBytes + 256;

  if (n == C * RS * RT && b >= 1 && ws_size >= need1) {
    float*        S      = (float*)d_ws;
    unsigned int* flags  = (unsigned int*)((char*)d_ws + sBytes);
    unsigned int* ticket = (unsigned int*)((char*)d_ws + sBytes + fBytes);
    (void)hipMemsetAsync((char*)d_ws + sBytes, 0, fBytes + 64, stream);
    hipLaunchKernelGGL(k_scan1, dim3(C * b), dim3(NT), 0, stream,
                       x, t, S, flags, ticket, o, b, n);
  } else if (n % C == 0 && (n / C) % RS == 0 && ws_size >= sBytes) {
    const int L = n / C;
    float* S = (float*)d_ws;
    hipLaunchKernelGGL(k_chunksum, dim3(C * b), dim3(DV * RS), 0, stream,
                       x, t, S, b, n, L);
    hipLaunchKernelGGL(k_out, dim3(C * b), dim3(DV), 0, stream,
                       x, t, S, o, b, n, L);
  } else {
    const int threads = b * DV;
    hipLaunchKernelGGL(k_naive, dim3((threads + 255) / 256), dim3(256), 0, stream,
                       x, t, o, b, n);
  }
}

// Round 4
// 267.502 us; speedup vs baseline: 1.6482x; 1.0686x over previous
//
#include <hip/hip_runtime.h>

// o[i,u,j] = sum_{v<=u} t[v,j] * x[i,v,j]
// x: (b, n, d) fp32, t: (2n-2, d) fp32 (first n rows used), o: (b, n, d) fp32

typedef float f4 __attribute__((ext_vector_type(4)));

#define D  512
#define DV (D / 4)    // 128 float4 columns
#define C  128        // chunks along sequence
#define RS 4          // row-group split inside a block
#define RT 16         // rows per thread (L = RS*RT = 64)
#define NT (DV * RS)  // 512 threads

// Write-through coherent 16B store (reaches coherence point, no cache sweep).
__device__ __forceinline__ void coh_store_f4(f4* p, f4 v) {
  asm volatile("global_store_dwordx4 %0, %1, off sc0 sc1"
               :: "v"(p), "v"(v) : "memory");
}

// ---------------- Single-pass decoupled-lookback scan, v3 ----------------
// v2 lesson (round 3 counters): __launch_bounds__(NT,6) demanded 24 waves/CU,
// which quantizes to a <=64-VGPR cap -> compiler rematerialized the product
// array from memory in phase C (VGPR_Count=40), re-reading x. v3: no
// min-waves bound (VGPR ~100, 16 waves/CU) + opaque keep-alive on p[] so
// the products genuinely stay in registers between phase A and phase C.
__global__ __launch_bounds__(NT) void k_scan1(
    const float* __restrict__ x, const float* __restrict__ t,
    float* S, unsigned int* flags, unsigned int* ticket,
    float* __restrict__ o, int b, int n) {
  __shared__ unsigned int s_vid;
  __shared__ f4 red[RS][DV];   // 8 KB, reused across phases

  const int tid = threadIdx.x;
  if (tid == 0)
    s_vid = __hip_atomic_fetch_add(ticket, 1u, __ATOMIC_RELAXED,
                                   __HIP_MEMORY_SCOPE_AGENT);
  __syncthreads();
  const int vid = (int)s_vid;          // start-order virtual block id
  const int c   = vid / b;             // chunk (monotone in start order)
  const int i   = vid - c * b;         // batch row
  const int jv  = tid & (DV - 1);
  const int h   = tid >> 7;            // row group 0..3
  const int L   = RS * RT;             // 64

  const size_t row0 = (size_t)c * L + (size_t)h * RT;
  const f4* xp = (const f4*)x + ((size_t)i * n + row0) * DV + jv;
  const f4* tp = (const f4*)t + row0 * DV + jv;

  // Phase A: read chunk once; products stay in VGPRs. x/t cached (x fits
  // L3 across iterations); o stores below are nontemporal so x stays.
  f4 p[RT];
  f4 psum = {0.f, 0.f, 0.f, 0.f};
#pragma unroll
  for (int r = 0; r < RT; ++r) {
    p[r] = xp[(size_t)r * DV] * tp[(size_t)r * DV];
    psum += p[r];
  }
  // Opaque redefinition: compiler cannot rematerialize p[] from x/t later.
#pragma unroll
  for (int r = 0; r < RT; ++r)
    asm volatile("" : "+v"(p[r]));
  red[h][jv] = psum;
  __syncthreads();

  // Within-chunk exclusive base for this row group (save now; red is reused).
  f4 baseL = {0.f, 0.f, 0.f, 0.f};
  for (int hp = 0; hp < h; ++hp) baseL += red[hp][jv];

  // Publish chunk aggregate write-through coherent, then relaxed flag.
  if (h == 0) {
    f4 s = red[0][jv] + red[1][jv] + red[2][jv] + red[3][jv];
    coh_store_f4((f4*)S + ((size_t)c * b + i) * DV + jv, s);
  }
  asm volatile("s_waitcnt vmcnt(0)" ::: "memory");
  __syncthreads();
  if (tid == 0)
    __hip_atomic_store(&flags[(size_t)i * C + c], 1u, __ATOMIC_RELAXED,
                       __HIP_MEMORY_SCOPE_AGENT);

  // Phase B: wave 0 polls predecessors' flags (contiguous -> coalesced).
  if (tid < 64) {
    const unsigned int* fp = flags + (size_t)i * C;
    const int c0 = tid, c1 = tid + 64;
    const bool need0 = c0 < c, need1 = c1 < c;
    for (;;) {
      bool ok0 = !need0 || (__hip_atomic_load(fp + c0, __ATOMIC_RELAXED,
                                              __HIP_MEMORY_SCOPE_AGENT) != 0u);
      bool ok1 = !need1 || (__hip_atomic_load(fp + c1, __ATOMIC_RELAXED,
                                              __HIP_MEMORY_SCOPE_AGENT) != 0u);
      if (__all(ok0 && ok1)) break;
      __builtin_amdgcn_s_sleep(2);
    }
  }
  __syncthreads();   // compiler + workgroup fence; S lines are fresh per-line

  // Exclusive prefix: plain pipelined loads of S.
  f4 ex = {0.f, 0.f, 0.f, 0.f};
  const f4* Sb = (const f4*)S;
#pragma unroll 8
  for (int cp = h; cp < c; cp += RS)
    ex += Sb[((size_t)cp * b + i) * DV + jv];
  red[h][jv] = ex;
  __syncthreads();
  f4 base = red[0][jv] + red[1][jv] + red[2][jv] + red[3][jv] + baseL;

  // Phase C: in-register scan + nontemporal stores (x never re-read).
  f4* op = (f4*)o + ((size_t)i * n + row0) * DV + jv;
  f4 acc = base;
#pragma unroll
  for (int r = 0; r < RT; ++r) {
    acc += p[r];
    __builtin_nontemporal_store(acc, op + (size_t)r * DV);
  }
}

// ---------------- Fallback: two-kernel pipeline ----------------
__global__ __launch_bounds__(DV * RS) void k_chunksum(
    const float* __restrict__ x, const float* __restrict__ t,
    float* __restrict__ S, int b, int n, int L) {
  const int c  = blockIdx.x / b;
  const int i  = blockIdx.x % b;
  const int jv = threadIdx.x & (DV - 1);
  const int h  = threadIdx.x >> 7;
  const int rows = L / RS;
  const size_t row0 = (size_t)c * L + (size_t)h * rows;
  const f4* xp = (const f4*)x + ((size_t)i * n + row0) * DV + jv;
  const f4* tp = (const f4*)t + row0 * DV + jv;
  f4 acc = {0.f, 0.f, 0.f, 0.f};
#pragma unroll 8
  for (int v = 0; v < rows; ++v) {
    acc += xp[(size_t)v * DV] * tp[(size_t)v * DV];
  }
  __shared__ f4 red[RS][DV];
  red[h][jv] = acc;
  __syncthreads();
  if (h == 0) {
    f4 s = red[0][jv] + red[1][jv] + red[2][jv] + red[3][jv];
    ((f4*)S)[((size_t)c * b + i) * DV + jv] = s;
  }
}

__global__ __launch_bounds__(DV) void k_out(
    const float* __restrict__ x, const float* __restrict__ t,
    const float* __restrict__ S, float* __restrict__ o, int b, int n, int L) {
  const int c  = blockIdx.x / b;
  const int i  = blockIdx.x % b;
  const int jv = threadIdx.x;
  f4 acc = {0.f, 0.f, 0.f, 0.f};
  const f4* Sp = (const f4*)S + (size_t)i * DV + jv;
  const size_t cstride = (size_t)b * DV;
#pragma unroll 8
  for (int cp = 0; cp < c; ++cp) {
    acc += Sp[(size_t)cp * cstride];
  }
  const size_t row0  = (size_t)c * L;
  const size_t xbase = ((size_t)i * n + row0) * DV + jv;
  const f4* xp = (const f4*)x + xbase;
  const f4* tp = (const f4*)t + row0 * DV + jv;
  f4*       op = (f4*)o + xbase;
#pragma unroll 4
  for (int v = 0; v < L; ++v) {
    acc += xp[(size_t)v * DV] * tp[(size_t)v * DV];
    op[(size_t)v * DV] = acc;
  }
}

__global__ __launch_bounds__(256) void k_naive(
    const float* __restrict__ x, const float* __restrict__ t,
    float* __restrict__ o, int b, int n) {
  const int tid = blockIdx.x * 256 + threadIdx.x;
  if (tid >= b * DV) return;
  const int i  = tid / DV;
  const int jv = tid % DV;
  const f4* xp = (const f4*)x + (size_t)i * n * DV + jv;
  const f4* tp = (const f4*)t + jv;
  f4*       op = (f4*)o + (size_t)i * n * DV + jv;
  f4 acc = {0.f, 0.f, 0.f, 0.f};
  for (int v = 0; v < n; ++v) {
    acc += xp[(size_t)v * DV] * tp[(size_t)v * DV];
    op[(size_t)v * DV] = acc;
  }
}

extern "C" void kernel_launch(void* const* d_in, const int* in_sizes, int n_in,
                              void* d_out, int out_size, void* d_ws, size_t ws_size,
                              hipStream_t stream) {
  const float* x = (const float*)d_in[0];
  const float* t = (const float*)d_in[1];
  float*       o = (float*)d_out;

  const long long t_elems = in_sizes[1];
  const int n = (int)((t_elems / D + 2) / 2);
  const int b = (int)((long long)in_sizes[0] / ((long long)n * D));

  const size_t sBytes = (size_t)C * b * D * sizeof(float);   // aggregates (2 MB)
  const size_t fBytes = (size_t)C * b * sizeof(unsigned);    // flags (4 KB)
  const size_t need1  = sBytes + fBytes + 256;

  if (n == C * RS * RT && b >= 1 && ws_size >= need1) {
    float*        S      = (float*)d_ws;
    unsigned int* flags  = (unsigned int*)((char*)d_ws + sBytes);
    unsigned int* ticket = (unsigned int*)((char*)d_ws + sBytes + fBytes);
    (void)hipMemsetAsync((char*)d_ws + sBytes, 0, fBytes + 64, stream);
    hipLaunchKernelGGL(k_scan1, dim3(C * b), dim3(NT), 0, stream,
                       x, t, S, flags, ticket, o, b, n);
  } else if (n % C == 0 && (n / C) % RS == 0 && ws_size >= sBytes) {
    const int L = n / C;
    float* S = (float*)d_ws;
    hipLaunchKernelGGL(k_chunksum, dim3(C * b), dim3(DV * RS), 0, stream,
                       x, t, S, b, n, L);
    hipLaunchKernelGGL(k_out, dim3(C * b), dim3(DV), 0, stream,
                       x, t, S, o, b, n, L);
  } else {
    const int threads = b * DV;
    hipLaunchKernelGGL(k_naive, dim3((threads + 255) / 256), dim3(256), 0, stream,
                       x, t, o, b, n);
  }
}